// Round 1
// baseline (592.404 us; speedup 1.0000x reference)
//
#include <hip/hip_runtime.h>

// Problem constants (B,H,W) = (16,512,512); upsample x2.
#define BATCH 16
#define HIN   512
#define WIN   512
#define HOUT  1024
#define WOUT  1024

// d_out layout: out[16,3,1024,1024] | x_mask[16,1,1024,1024] | y_mask[16,1,1024,1024]
#define OUT_ELEMS   ((size_t)BATCH * 3 * HOUT * WOUT)
#define MASK_ELEMS  ((size_t)BATCH * HOUT * WOUT)

__global__ __launch_bounds__(256) void fused_upsample_conv_kernel(
    const float* __restrict__ mask,   // (16,2,512,512)
    const float* __restrict__ xl,     // (16,3,1024,1024)
    const float* __restrict__ yl,     // (16,3,1024,1024)
    const float* __restrict__ cw,     // (3,3) row-major: cw[o*3+i]
    const float* __restrict__ cb,     // (3,)
    float* __restrict__ out)
{
    const int oh = blockIdx.x;          // output row 0..1023
    const int b  = blockIdx.y;          // batch 0..15
    const int tx = threadIdx.x;         // 0..255
    const int ow0 = tx * 4;             // 4 output pixels per thread

    // ---- vertical (row) bilinear: half-pixel centers, clamped edges ----
    const int r = oh >> 1;
    int rA, rB; float wyA, wyB;
    if (oh & 1) { rA = r;                  rB = (r + 1 < HIN) ? r + 1 : HIN - 1; wyA = 0.75f; wyB = 0.25f; }
    else        { rA = (r > 0) ? r - 1 : 0; rB = r;                              wyA = 0.25f; wyB = 0.75f; }

    // ---- horizontal stencil: input cols 2t-1 .. 2t+2 (clamped) ----
    const int t2 = tx * 2;
    const int cM = (t2 > 0) ? t2 - 1 : 0;
    const int c0 = t2;
    const int c1 = t2 + 1;
    const int c2 = (t2 + 2 < WIN) ? t2 + 2 : WIN - 1;

    const size_t mplane = (size_t)HIN * WIN;
    const float* m0A = mask + ((size_t)b * 2 + 0) * mplane + (size_t)rA * WIN;
    const float* m0B = mask + ((size_t)b * 2 + 0) * mplane + (size_t)rB * WIN;
    const float* m1A = mask + ((size_t)b * 2 + 1) * mplane + (size_t)rA * WIN;
    const float* m1B = mask + ((size_t)b * 2 + 1) * mplane + (size_t)rB * WIN;

    float v0[4], v1[4];
    const int cols[4] = {cM, c0, c1, c2};
#pragma unroll
    for (int j = 0; j < 4; ++j) {
        v0[j] = wyA * m0A[cols[j]] + wyB * m0B[cols[j]];
        v1[j] = wyA * m1A[cols[j]] + wyB * m1B[cols[j]];
    }

    // ---- horizontal lerp -> 4 mask values per channel ----
    // ow0+0 (even,k=2t):   0.25*v[cM] + 0.75*v[c0]
    // ow0+1 (odd, k=2t):   0.75*v[c0] + 0.25*v[c1]
    // ow0+2 (even,k=2t+1): 0.25*v[c0] + 0.75*v[c1]
    // ow0+3 (odd, k=2t+1): 0.75*v[c1] + 0.25*v[c2]
    float4 xm, ym;
    xm.x = 0.25f*v0[0] + 0.75f*v0[1];
    xm.y = 0.75f*v0[1] + 0.25f*v0[2];
    xm.z = 0.25f*v0[1] + 0.75f*v0[2];
    xm.w = 0.75f*v0[2] + 0.25f*v0[3];
    ym.x = 0.25f*v1[0] + 0.75f*v1[1];
    ym.y = 0.75f*v1[1] + 0.25f*v1[2];
    ym.z = 0.25f*v1[1] + 0.75f*v1[2];
    ym.w = 0.75f*v1[2] + 0.25f*v1[3];

    // ---- conv weights/bias (wave-uniform, cached) ----
    const float w00 = cw[0], w01 = cw[1], w02 = cw[2];
    const float w10 = cw[3], w11 = cw[4], w12 = cw[5];
    const float w20 = cw[6], w21 = cw[7], w22 = cw[8];
    const float b0 = cb[0], b1 = cb[1], b2 = cb[2];

    const size_t oplane = (size_t)HOUT * WOUT;
    const size_t rowoff = (size_t)oh * WOUT + ow0;

    const float4 x0 = *(const float4*)(xl + ((size_t)b * 3 + 0) * oplane + rowoff);
    const float4 x1 = *(const float4*)(xl + ((size_t)b * 3 + 1) * oplane + rowoff);
    const float4 x2 = *(const float4*)(xl + ((size_t)b * 3 + 2) * oplane + rowoff);
    const float4 y0 = *(const float4*)(yl + ((size_t)b * 3 + 0) * oplane + rowoff);
    const float4 y1 = *(const float4*)(yl + ((size_t)b * 3 + 1) * oplane + rowoff);
    const float4 y2 = *(const float4*)(yl + ((size_t)b * 3 + 2) * oplane + rowoff);

    // fused_i = xm * xl_i + ym * yl_i
    float4 f0, f1, f2;
    f0.x = xm.x*x0.x + ym.x*y0.x;  f0.y = xm.y*x0.y + ym.y*y0.y;
    f0.z = xm.z*x0.z + ym.z*y0.z;  f0.w = xm.w*x0.w + ym.w*y0.w;
    f1.x = xm.x*x1.x + ym.x*y1.x;  f1.y = xm.y*x1.y + ym.y*y1.y;
    f1.z = xm.z*x1.z + ym.z*y1.z;  f1.w = xm.w*x1.w + ym.w*y1.w;
    f2.x = xm.x*x2.x + ym.x*y2.x;  f2.y = xm.y*x2.y + ym.y*y2.y;
    f2.z = xm.z*x2.z + ym.z*y2.z;  f2.w = xm.w*x2.w + ym.w*y2.w;

    // out_o = relu(w_o0*f0 + w_o1*f1 + w_o2*f2 + b_o)
    float4 o0, o1, o2;
    o0.x = fmaxf(w00*f0.x + w01*f1.x + w02*f2.x + b0, 0.0f);
    o0.y = fmaxf(w00*f0.y + w01*f1.y + w02*f2.y + b0, 0.0f);
    o0.z = fmaxf(w00*f0.z + w01*f1.z + w02*f2.z + b0, 0.0f);
    o0.w = fmaxf(w00*f0.w + w01*f1.w + w02*f2.w + b0, 0.0f);
    o1.x = fmaxf(w10*f0.x + w11*f1.x + w12*f2.x + b1, 0.0f);
    o1.y = fmaxf(w10*f0.y + w11*f1.y + w12*f2.y + b1, 0.0f);
    o1.z = fmaxf(w10*f0.z + w11*f1.z + w12*f2.z + b1, 0.0f);
    o1.w = fmaxf(w10*f0.w + w11*f1.w + w12*f2.w + b1, 0.0f);
    o2.x = fmaxf(w20*f0.x + w21*f1.x + w22*f2.x + b2, 0.0f);
    o2.y = fmaxf(w20*f0.y + w21*f1.y + w22*f2.y + b2, 0.0f);
    o2.z = fmaxf(w20*f0.z + w21*f1.z + w22*f2.z + b2, 0.0f);
    o2.w = fmaxf(w20*f0.w + w21*f1.w + w22*f2.w + b2, 0.0f);

    // ---- stores ----
    *(float4*)(out + ((size_t)b * 3 + 0) * oplane + rowoff) = o0;
    *(float4*)(out + ((size_t)b * 3 + 1) * oplane + rowoff) = o1;
    *(float4*)(out + ((size_t)b * 3 + 2) * oplane + rowoff) = o2;
    *(float4*)(out + OUT_ELEMS + (size_t)b * oplane + rowoff) = xm;
    *(float4*)(out + OUT_ELEMS + MASK_ELEMS + (size_t)b * oplane + rowoff) = ym;
}

extern "C" void kernel_launch(void* const* d_in, const int* in_sizes, int n_in,
                              void* d_out, int out_size, void* d_ws, size_t ws_size,
                              hipStream_t stream) {
    const float* mask = (const float*)d_in[0];
    const float* xl   = (const float*)d_in[1];
    const float* yl   = (const float*)d_in[2];
    const float* cw   = (const float*)d_in[3];
    const float* cb   = (const float*)d_in[4];
    float* out = (float*)d_out;

    dim3 grid(HOUT, BATCH);   // one block per (output row, batch)
    dim3 block(256);          // 256 threads x 4 px = 1024-wide row
    fused_upsample_conv_kernel<<<grid, block, 0, stream>>>(mask, xl, yl, cw, cb, out);
}